// Round 6
// baseline (1556.891 us; speedup 1.0000x reference)
//
#include <hip/hip_runtime.h>

// ---------------------------------------------------------------------------
// BLSTM: emb gather -> fwd LSTM scan + bwd single-step -> [2048,512] @ fc_w^T
// B=16 S=128 V=32000 D=H=256.  Output logits [16,128,32000] fp32.
//
// R7 (k2m): the scan is now a per-step MFMA GEMM on ONE block (1 CU).
// Why: R3-R6 proved the allocator pins arch VGPRs at 128 for 512-thr blocks
// and demotes big arrays to AGPRs; VOP3P can't source AGPRs (184 accvgpr
// reads/step = 71% active VALUBusy at 258us).  MFMA is the one consumer
// that reads AGPRs directly -> weights live as 64 B-fragments (256 dwords)
// in AGPRs by design.  P[16b][1024n] = H @ W_hh^T, M=16 = one MFMA tile.
// Wave w owns units [32w,32w+32) x all 4 gates -> C-layout puts i,f,g,o of
// each (batch,unit) in the SAME lane/reg -> thread-local gate combine.
// xp folded as MFMA C-init: k1 writes xp pre-swizzled to fragment order
// (xpT); k2m inits acc via 8 coalesced float4 loads/lane/step (prefetched).
// H f16 dbl-buffered in LDS (rows padded to 272h = 544B, 4-way max alias);
// ONE lgkm-only barrier/step.  k3 (fc_w->bf16) fused in as blocks 1..2000
// (independent work, overlaps scan on the other 255 CUs).
// Model: MFMA 620cy + LDS ~1150cy + VALU ~1100cy -> ~2000cy/step -> ~110us.
// ---------------------------------------------------------------------------

#define Bz 16
#define Sq 128
#define Vv 32000
#define Dd 256
#define Hh 256
#define Ktot  (2 * Hh)         // 512
#define HPAD 272               // H row stride in halves (544 B)

typedef __bf16 bf16x8 __attribute__((ext_vector_type(8)));
typedef _Float16 f16x8 __attribute__((ext_vector_type(8)));
typedef float  f32x4  __attribute__((ext_vector_type(4)));

__device__ __forceinline__ unsigned short f2bf(float x) {
  union { float f; unsigned u; } v; v.f = x;
  unsigned r = (v.u + 0x7FFFu + ((v.u >> 16) & 1u)) >> 16;
  return (unsigned short)r;
}
__device__ __forceinline__ float sigm(float x) { return 1.f / (1.f + __expf(-x)); }
__device__ __forceinline__ float tanh_(float x) { return 2.f / (1.f + __expf(-2.f * x)) - 1.f; }
__device__ __forceinline__ void fma4(float4& a, const float4 w, const float s) {
  a.x = fmaf(w.x, s, a.x); a.y = fmaf(w.y, s, a.y);
  a.z = fmaf(w.z, s, a.z); a.w = fmaf(w.w, s, a.w);
}
__device__ __forceinline__ unsigned pkh(float x, float y) {
  const unsigned short lo = __builtin_bit_cast(unsigned short, (_Float16)x);
  const unsigned short hi = __builtin_bit_cast(unsigned short, (_Float16)y);
  return ((unsigned)hi << 16) | (unsigned)lo;
}
// LDS-only barrier: order ds ops, do NOT drain vmcnt (keeps global prefetch
// in flight across the barrier).  Single asm block with "memory" clobber.
__device__ __forceinline__ void bar() {
  asm volatile("s_waitcnt lgkmcnt(0)\n\ts_barrier" ::: "memory");
}

// --------------------------------------------------------------------------
// K0: transpose+pack input weights to [k][j] float4 (i,f,g,o), fold biases.
// grid (256, 2), block 256.
// --------------------------------------------------------------------------
__global__ __launch_bounds__(256) void k0_pack(
    const float* __restrict__ w_ih_f, const float* __restrict__ w_ih_b,
    const float* __restrict__ b_ih_f, const float* __restrict__ b_hh_f,
    const float* __restrict__ b_ih_b, const float* __restrict__ b_hh_b,
    float4* __restrict__ wPackF, float4* __restrict__ wPackB,
    float4* __restrict__ biasF, float4* __restrict__ biasB)
{
  const int j = threadIdx.x;   // output column 0..255
  const int k = blockIdx.x;    // input dim 0..255
  const int g = blockIdx.y;    // 0: w_ih_f, 1: w_ih_b
  const float* src = (g == 0) ? w_ih_f : w_ih_b;
  float4* dst = (g == 0) ? wPackF : wPackB;
  float4 v;
  v.x = src[(j      ) * 256 + k];
  v.y = src[(j + 256) * 256 + k];
  v.z = src[(j + 512) * 256 + k];
  v.w = src[(j + 768) * 256 + k];
  dst[k * 256 + j] = v;
  if (k == 0 && g == 0) {
    float4 b;
    b.x = b_ih_f[j      ] + b_hh_f[j      ];
    b.y = b_ih_f[j + 256] + b_hh_f[j + 256];
    b.z = b_ih_f[j + 512] + b_hh_f[j + 512];
    b.w = b_ih_f[j + 768] + b_hh_f[j + 768];
    biasF[j] = b;
  }
  if (k == 0 && g == 1) {
    float4 b;
    b.x = b_ih_b[j      ] + b_hh_b[j      ];
    b.y = b_ih_b[j + 256] + b_hh_b[j + 256];
    b.z = b_ih_b[j + 512] + b_hh_b[j + 512];
    b.w = b_ih_b[j + 768] + b_hh_b[j + 768];
    biasB[j] = b;
  }
}

// --------------------------------------------------------------------------
// K1: embedding gather + input projections. grid (128, 2): y=0 -> xpT
// (xp pre-swizzled into k2m's MFMA C-fragment order), y=1 -> backward
// single-step cell -> hb (bf16, right half of the GEMM A matrix).
//
// xpT f32 index for (b, t, n=q*256+u):
//   w=u>>5, h=(u>>4)&1, l15=u&15, lane=(b>>2)*16+l15, r=b&3
//   idx = ((t*8 + w)*8 + q*2 + h)*256 + lane*4 + r
// --------------------------------------------------------------------------
__global__ __launch_bounds__(256) void k1_embproj(
    const int* __restrict__ x, const float* __restrict__ embed,
    const float4* __restrict__ wPackF, const float4* __restrict__ wPackB,
    const float4* __restrict__ biasF, const float4* __restrict__ biasB,
    float* __restrict__ xpT, unsigned short* __restrict__ outB)
{
  __shared__ __align__(16) float e[16][256];
  __shared__ int xi[16];
  const int j = threadIdx.x;
  const int m0 = blockIdx.x * 16;
  const int dir = blockIdx.y;
  if (j < 16) xi[j] = x[m0 + j];
  __syncthreads();
#pragma unroll
  for (int m = 0; m < 16; ++m) e[m][j] = embed[(size_t)xi[m] * Dd + j];
  __syncthreads();

  const float4* wP = dir ? wPackB : wPackF;
  float4 acc[16];
#pragma unroll
  for (int m = 0; m < 16; ++m) acc[m] = make_float4(0.f, 0.f, 0.f, 0.f);

  for (int k = 0; k < 256; k += 4) {
    const float4 w0 = wP[(k + 0) * 256 + j];
    const float4 w1 = wP[(k + 1) * 256 + j];
    const float4 w2 = wP[(k + 2) * 256 + j];
    const float4 w3 = wP[(k + 3) * 256 + j];
#pragma unroll
    for (int m = 0; m < 16; ++m) {
      const float4 e4 = *(const float4*)&e[m][k];
      fma4(acc[m], w0, e4.x); fma4(acc[m], w1, e4.y);
      fma4(acc[m], w2, e4.z); fma4(acc[m], w3, e4.w);
    }
  }

  if (dir == 0) {
    const float4 bv = biasF[j];
    const int wv = j >> 5, hh = (j >> 4) & 1, l15 = j & 15;
#pragma unroll
    for (int m = 0; m < 16; ++m) {
      const int mb = m0 + m;
      const int b = mb >> 7, t = mb & 127;
      const int lane = (b >> 2) * 16 + l15, r = b & 3;
      float* xq = xpT + (size_t)(((t * 8 + wv) * 8 + hh) * 256 + lane * 4 + r);
      float4 v = acc[m];
      xq[0]    = v.x + bv.x;     // q=0 (i)
      xq[512]  = v.y + bv.y;     // q=1 (f)
      xq[1024] = v.z + bv.z;     // q=2 (g)
      xq[1536] = v.w + bv.w;     // q=3 (o)
    }
  } else {
    const float4 bv = biasB[j];
#pragma unroll
    for (int m = 0; m < 16; ++m) {
      float4 v = acc[m];
      v.x += bv.x; v.y += bv.y; v.z += bv.z; v.w += bv.w;
      const float ig = sigm(v.x);
      const float gg = tanh_(v.z);
      const float og = sigm(v.w);
      const float hb = og * tanh_(ig * gg);
      outB[(size_t)(m0 + m) * Ktot + Hh + j] = f2bf(hb);
    }
  }
}

// --------------------------------------------------------------------------
// KW2: W_hh fp32 [1024][256] -> f16 MFMA B-fragments.
// wq2[j*512 + t] (uint4 = 8 f16), t=(wave w=t>>6, lane l=t&63),
// j=(q*2+h)*8+kc: W[row = q*256 + w*32 + h*16 + (l&15)]
//                  [k  = kc*32 + (l>>4)*8 .. +8].
// grid 128 x 256 (one uint4 per thread).  k2m's weight load is then fully
// lane-coalesced (wq2[j*512 + tid]).
// --------------------------------------------------------------------------
__global__ __launch_bounds__(256) void kw2_cvt(const float* __restrict__ s,
                                               uint4* __restrict__ d)
{
  const int g = blockIdx.x * 256 + threadIdx.x;   // 0..32767
  const int t = g & 511, j = g >> 9;
  const int wv = t >> 6, l = t & 63;
  const int q = j >> 4, h = (j >> 3) & 1, kc = j & 7;
  const int row = q * 256 + wv * 32 + h * 16 + (l & 15);
  const int kb  = kc * 32 + (l >> 4) * 8;
  const float4 a  = *(const float4*)(s + (size_t)row * 256 + kb);
  const float4 bq = *(const float4*)(s + (size_t)row * 256 + kb + 4);
  d[(size_t)j * 512 + t] =
      make_uint4(pkh(a.x, a.y), pkh(a.z, a.w), pkh(bq.x, bq.y), pkh(bq.z, bq.w));
}

// --------------------------------------------------------------------------
// K2m: forward LSTM scan as per-step MFMA GEMM.  Block 0 (512 thr, 8 waves)
// does the scan on one CU; blocks 1.. do the fc_w fp32->bf16 conversion
// (independent, overlaps on other CUs).
// Per step: acc[q][h] (4 gates x 2 unit-halves) = xpT C-frag; 8 A-frags
// from H LDS; 64 mfma_f32_16x16x32_f16 (B-frags = AGPR-resident weights);
// thread-local gate combine; h -> H LDS (other buffer) + outB; 1 barrier.
// --------------------------------------------------------------------------
__global__ __launch_bounds__(512) void k2m(
    const uint4* __restrict__ wq2,    // [64][512] uint4 f16 B-fragments
    const float4* __restrict__ xpT,   // [8192][64] float4 (C-frag order)
    unsigned short* __restrict__ outB,
    const float4* __restrict__ fcw,   // fused k3: fc_w fp32
    uint2* __restrict__ fcwB)         //          -> bf16
{
  if (blockIdx.x != 0) {
    // ---- fused fc_w converter: 4,096,000 float4, grid-stride ----
    const size_t stride = (size_t)(gridDim.x - 1) * 512;
    for (size_t i = (size_t)(blockIdx.x - 1) * 512 + threadIdx.x;
         i < 4096000u; i += stride) {
      const float4 v = fcw[i];
      uint2 r;
      r.x = (unsigned)f2bf(v.x) | ((unsigned)f2bf(v.y) << 16);
      r.y = (unsigned)f2bf(v.z) | ((unsigned)f2bf(v.w) << 16);
      fcwB[i] = r;
    }
    return;
  }

  // ---- scan block ----
  __shared__ __align__(16) unsigned short Hb[2][16][HPAD];

  const int tid = threadIdx.x;
  const int w   = tid >> 6;         // wave 0..7: units [32w, 32w+32)
  const int l   = tid & 63;
  const int l15 = l & 15;
  const int lq  = l >> 4;           // quad 0..3

  // one-time: weights -> 64 B-fragments (256 dwords; allocator -> AGPRs,
  // MFMA reads them directly).  Fully coalesced loads.
  uint4 wB[4][2][8];
#pragma unroll
  for (int q = 0; q < 4; ++q)
#pragma unroll
    for (int h = 0; h < 2; ++h)
#pragma unroll
      for (int kc = 0; kc < 8; ++kc)
        wB[q][h][kc] = wq2[(size_t)(((q * 2 + h) * 8 + kc)) * 512 + tid];

  // zero H buffer 0 (t=0 reads it)
  {
    unsigned short* hz = &Hb[0][0][0];
    for (int i = tid; i < 16 * HPAD; i += 512) hz[i] = 0;
  }

  // xp C-fragment prefetch for t=0: xf[qh] = xpT[((t*8+w)*8+qh)*64 + l]
  float4 xf[8];
#pragma unroll
  for (int qh = 0; qh < 8; ++qh)
    xf[qh] = xpT[(size_t)((0 * 8 + w) * 8 + qh) * 64 + l];

  float c8[2][4] = {};              // cell state: [h][r]
  bar();                            // Hb[0] zeroed

#pragma unroll 1
  for (int t = 0; t < Sq; ++t) {
    // acc init from xp fragment (C-layout: col=l15=unit, row=lq*4+r=batch)
    f32x4 acc[4][2];
#pragma unroll
    for (int q = 0; q < 4; ++q)
#pragma unroll
      for (int h = 0; h < 2; ++h)
        acc[q][h] = __builtin_bit_cast(f32x4, xf[q * 2 + h]);

    // prefetch next step's xp (vmcnt: survives the lgkm-only barrier)
    if (t + 1 < Sq) {
#pragma unroll
      for (int qh = 0; qh < 8; ++qh)
        xf[qh] = xpT[(size_t)(((t + 1) * 8 + w) * 8 + qh) * 64 + l];
    }

    // A-fragments from H: lane holds H[b=l15][k = kc*32 + lq*8 .. +8]
    uint4 afr[8];
#pragma unroll
    for (int kc = 0; kc < 8; ++kc)
      afr[kc] = *(const uint4*)&Hb[t & 1][l15][kc * 32 + lq * 8];

    // 64 MFMA: acc[q][h] += A(kc) * W-frag[q][h][kc]
#pragma unroll
    for (int kc = 0; kc < 8; ++kc) {
      const f16x8 a = __builtin_bit_cast(f16x8, afr[kc]);
#pragma unroll
      for (int q = 0; q < 4; ++q)
#pragma unroll
        for (int h = 0; h < 2; ++h)
          acc[q][h] = __builtin_amdgcn_mfma_f32_16x16x32_f16(
              a, __builtin_bit_cast(f16x8, wB[q][h][kc]), acc[q][h], 0, 0, 0);
    }

    // thread-local gate combine: i,f,g,o of (b = lq*4+r, u = w*32+h*16+l15)
    // all sit in this lane at reg r of acc[0..3][h].
#pragma unroll
    for (int h = 0; h < 2; ++h) {
      const int u = w * 32 + h * 16 + l15;
#pragma unroll
      for (int r = 0; r < 4; ++r) {
        const int b = lq * 4 + r;
        const float ig = sigm(acc[0][h][r]);
        const float fg = sigm(acc[1][h][r]);
        const float gg = tanh_(acc[2][h][r]);
        const float og = sigm(acc[3][h][r]);
        const float c = fg * c8[h][r] + ig * gg;
        c8[h][r] = c;
        const float hn = og * tanh_(c);
        Hb[(t + 1) & 1][b][u] =
            __builtin_bit_cast(unsigned short, (_Float16)hn);
        outB[((size_t)(b * Sq + t) << 9) + u] = f2bf(hn);
      }
    }
    bar();   // h_t published (other buffer); this step's reads done
  }
}

// --------------------------------------------------------------------------
// K4: logits = [2048,512](bf16) x fc_w^T (fc_w [32000,512] bf16, B^T layout)
// + fc_b.  128x128 tile, BK=64, 4 waves, global_load_lds width-16 staging.
// --------------------------------------------------------------------------
__device__ __forceinline__ void load_lds_16(const void* g, void* l) {
  __builtin_amdgcn_global_load_lds(
      (const __attribute__((address_space(1))) unsigned int*)g,
      (__attribute__((address_space(3))) unsigned int*)l, 16, 0, 0);
}

__global__ __launch_bounds__(256) void k4_gemm(
    const unsigned short* __restrict__ A,   // [2048][512] bf16
    const unsigned short* __restrict__ Bm,  // [32000][512] bf16
    const float* __restrict__ fcb,          // [32000]
    float* __restrict__ out)                // [2048][32000]
{
  __shared__ __align__(16) char smem[32768];
  const int tid  = threadIdx.x;
  const int wave = tid >> 6;
  const int lane = tid & 63;
  const int bm = blockIdx.x;      // 0..15  (M tiles)
  const int bn = blockIdx.y;      // 0..249 (N tiles)
  const int wm = (wave >> 1) * 64;
  const int wn = (wave & 1) * 64;
  const int quad = lane >> 4;
  const int r16  = lane & 15;

  f32x4 acc[4][4] = {};

  const unsigned short* Ag = A  + ((size_t)(bm * 128) + (tid >> 3)) * Ktot + (tid & 7) * 8;
  const unsigned short* Bg = Bm + ((size_t)(bn * 128) + (tid >> 3)) * Ktot + (tid & 7) * 8;
  char* AsW = smem + wave * 1024;
  char* BsW = smem + 16384 + wave * 1024;

  for (int kt = 0; kt < 8; ++kt) {
    const int k0 = kt * 64;
#pragma unroll
    for (int r = 0; r < 4; ++r) {
      load_lds_16(Ag + (size_t)r * 32 * Ktot + k0, AsW + r * 4096);
      load_lds_16(Bg + (size_t)r * 32 * Ktot + k0, BsW + r * 4096);
    }
    __syncthreads();
#pragma unroll
    for (int kk = 0; kk < 2; ++kk) {
      bf16x8 af[4], bfr[4];
#pragma unroll
      for (int i = 0; i < 4; ++i) {
        const int rowA = wm + i * 16 + r16;
        af[i] = *(const bf16x8*)(smem + rowA * 128 + kk * 64 + quad * 16);
        const int rowB = wn + i * 16 + r16;
        bfr[i] = *(const bf16x8*)(smem + 16384 + rowB * 128 + kk * 64 + quad * 16);
      }
#pragma unroll
      for (int i = 0; i < 4; ++i)
#pragma unroll
        for (int j = 0; j < 4; ++j)
          acc[i][j] = __builtin_amdgcn_mfma_f32_16x16x32_bf16(af[i], bfr[j], acc[i][j], 0, 0, 0);
    }
    __syncthreads();
  }

#pragma unroll
  for (int j = 0; j < 4; ++j) {
    const int col = bn * 128 + wn + j * 16 + r16;
    const float bias = fcb[col];
#pragma unroll
    for (int i = 0; i < 4; ++i) {
      const int row0 = bm * 128 + wm + i * 16 + quad * 4;
#pragma unroll
      for (int r = 0; r < 4; ++r) {
        out[(size_t)(row0 + r) * Vv + col] = acc[i][j][r] + bias;
      }
    }
  }
}

// --------------------------------------------------------------------------
extern "C" void kernel_launch(void* const* d_in, const int* in_sizes, int n_in,
                              void* d_out, int out_size, void* d_ws, size_t ws_size,
                              hipStream_t stream) {
  const int*   x      = (const int*)d_in[0];
  const float* embed  = (const float*)d_in[1];
  const float* w_ih_f = (const float*)d_in[2];
  const float* w_hh_f = (const float*)d_in[3];
  const float* b_ih_f = (const float*)d_in[4];
  const float* b_hh_f = (const float*)d_in[5];
  const float* w_ih_b = (const float*)d_in[6];
  // d_in[7] = w_hh_b: unused (backward direction is a zero-state single step)
  const float* b_ih_b = (const float*)d_in[8];
  const float* b_hh_b = (const float*)d_in[9];
  const float* fc_w   = (const float*)d_in[10];
  const float* fc_b   = (const float*)d_in[11];
  float* out = (float*)d_out;

  // Workspace layout (peak 45.4 MB; wq2 overlays wPackF which is dead after
  // k1 -- kw2_cvt MUST launch after k1):
  char* ws = (char*)d_ws;
  float4* wPackF = (float4*)(ws + 0x000000);            // 1 MB   (k0 w, k1 r)
  float4* wPackB = (float4*)(ws + 0x100000);            // 1 MB   (k0 w, k1 r)
  uint4*  wq2    = (uint4*)(ws + 0x000000);             // 512 KB (kw2 w, k2m r)
  float*  xpT    = (float*)(ws + 0x200000);             // 8 MB   (k1 w, k2m r)
  float4* biasF  = (float4*)(ws + 0xA00000);            // 4 KB
  float4* biasB  = (float4*)(ws + 0xA01000);            // 4 KB
  unsigned short* outB = (unsigned short*)(ws + 0xA05000);   // 2 MB [2048][512]
  unsigned short* fcwB = (unsigned short*)(ws + 0xC05000);   // 31.25 MiB

  k0_pack<<<dim3(256, 2), 256, 0, stream>>>(w_ih_f, w_ih_b,
                                            b_ih_f, b_hh_f, b_ih_b, b_hh_b,
                                            wPackF, wPackB, biasF, biasB);
  k1_embproj<<<dim3(128, 2), 256, 0, stream>>>(x, embed, wPackF, wPackB,
                                               biasF, biasB, xpT, outB);
  kw2_cvt<<<128, 256, 0, stream>>>(w_hh_f, wq2);
  k2m<<<2001, 512, 0, stream>>>(wq2, (const float4*)xpT, outB,
                                (const float4*)fc_w, (uint2*)fcwB);
  k4_gemm<<<dim3(16, 250), 256, 0, stream>>>(outB, fcwB, fc_b, out);
}

// Round 7
// 734.013 us; speedup vs baseline: 2.1211x; 2.1211x over previous
//
#include <hip/hip_runtime.h>

// ---------------------------------------------------------------------------
// BLSTM: emb gather -> fwd LSTM scan + bwd single-step -> [2048,512] @ fc_w^T
// B=16 S=128 V=32000 D=H=256.  Output logits [16,128,32000] fp32.
//
// R8: revert scan to R6's k2h (proven 257.8us; R7's k2m spilled: at 2
// waves/SIMD the UNIFIED budget is 256 dwords/wave, k2m needed ~420 ->
// scratch, 1090us).  Three attributable changes:
//  1. k2h: waves_per_eu(2,2) -> waves_per_eu(1) (min-only).  (2,2) forced
//     two waves into the unified file -> 128 arch VGPRs -> ~150 weight
//     dwords in AGPRs -> v_accvgpr_read tax (VOP3P can't source AGPRs),
//     71% active VALUBusy.  Min-only lets the allocator grant ~230 arch
//     VGPRs (2x230 <= 512 still runs 2 waves/EU).  Downside bounded: if
//     ignored we stay at 258us.
//  2. k3 fused into k1 as blockIdx.y==2 plane (overlaps 47MB conversion
//     with k1/kw instead of a serialized dispatch).
//  3. k4: bijective XCD swizzle (1D grid 4000) so all 16 bm-tiles of one
//     bn share an XCD-L2 (B-tile fetched once per L2 instead of 8x).
// ---------------------------------------------------------------------------

#define Bz 16
#define Sq 128
#define Vv 32000
#define Dd 256
#define Hh 256
#define Ktot  (2 * Hh)         // 512

#define NW_V 23   // weight chunks (uint4 = 8 f16) per row in VGPRs
#define NW_L 9    // weight chunks per row in LDS   (NW_V+NW_L == 32)

typedef __bf16 bf16x8 __attribute__((ext_vector_type(8)));
typedef float  f32x4  __attribute__((ext_vector_type(4)));
typedef _Float16 f16x2 __attribute__((ext_vector_type(2)));

__device__ __forceinline__ unsigned short f2bf(float x) {
  union { float f; unsigned u; } v; v.f = x;
  unsigned r = (v.u + 0x7FFFu + ((v.u >> 16) & 1u)) >> 16;
  return (unsigned short)r;
}
__device__ __forceinline__ float sigm(float x) { return 1.f / (1.f + __expf(-x)); }
__device__ __forceinline__ float tanh_(float x) { return 2.f / (1.f + __expf(-2.f * x)) - 1.f; }
__device__ __forceinline__ void fma4(float4& a, const float4 w, const float s) {
  a.x = fmaf(w.x, s, a.x); a.y = fmaf(w.y, s, a.y);
  a.z = fmaf(w.z, s, a.z); a.w = fmaf(w.w, s, a.w);
}
__device__ __forceinline__ unsigned pkh(float x, float y) {
  const unsigned short lo = __builtin_bit_cast(unsigned short, (_Float16)x);
  const unsigned short hi = __builtin_bit_cast(unsigned short, (_Float16)y);
  return ((unsigned)hi << 16) | (unsigned)lo;
}
// packed f16 MAC: acc(v2f16) += w(v2f16) * h(v2f16)  -> v_pk_fma_f16
__device__ __forceinline__ f16x2 fma2(unsigned w, unsigned h, f16x2 acc) {
  const f16x2 wv = __builtin_bit_cast(f16x2, w);
  const f16x2 hv = __builtin_bit_cast(f16x2, h);
#if __has_builtin(__builtin_elementwise_fma)
  return __builtin_elementwise_fma(wv, hv, acc);
#else
  return wv * hv + acc;   // -ffp-contract fuses to v_pk_fma_f16
#endif
}
// LDS-only barrier: order ds ops, do NOT drain vmcnt (keeps global prefetch
// in flight across the barrier).  Single asm block with "memory" clobber.
__device__ __forceinline__ void bar() {
  asm volatile("s_waitcnt lgkmcnt(0)\n\ts_barrier" ::: "memory");
}

// --------------------------------------------------------------------------
// K0: transpose+pack input weights to [k][j] float4 (i,f,g,o), fold biases.
// grid (256, 2), block 256.
// --------------------------------------------------------------------------
__global__ __launch_bounds__(256) void k0_pack(
    const float* __restrict__ w_ih_f, const float* __restrict__ w_ih_b,
    const float* __restrict__ b_ih_f, const float* __restrict__ b_hh_f,
    const float* __restrict__ b_ih_b, const float* __restrict__ b_hh_b,
    float4* __restrict__ wPackF, float4* __restrict__ wPackB,
    float4* __restrict__ biasF, float4* __restrict__ biasB)
{
  const int j = threadIdx.x;   // output column 0..255
  const int k = blockIdx.x;    // input dim 0..255
  const int g = blockIdx.y;    // 0: w_ih_f, 1: w_ih_b
  const float* src = (g == 0) ? w_ih_f : w_ih_b;
  float4* dst = (g == 0) ? wPackF : wPackB;
  float4 v;
  v.x = src[(j      ) * 256 + k];
  v.y = src[(j + 256) * 256 + k];
  v.z = src[(j + 512) * 256 + k];
  v.w = src[(j + 768) * 256 + k];
  dst[k * 256 + j] = v;
  if (k == 0 && g == 0) {
    float4 b;
    b.x = b_ih_f[j      ] + b_hh_f[j      ];
    b.y = b_ih_f[j + 256] + b_hh_f[j + 256];
    b.z = b_ih_f[j + 512] + b_hh_f[j + 512];
    b.w = b_ih_f[j + 768] + b_hh_f[j + 768];
    biasF[j] = b;
  }
  if (k == 0 && g == 1) {
    float4 b;
    b.x = b_ih_b[j      ] + b_hh_b[j      ];
    b.y = b_ih_b[j + 256] + b_hh_b[j + 256];
    b.z = b_ih_b[j + 512] + b_hh_b[j + 512];
    b.w = b_ih_b[j + 768] + b_hh_b[j + 768];
    biasB[j] = b;
  }
}

// --------------------------------------------------------------------------
// K1: embedding gather + input projections + fused fc_w converter.
// grid (128, 3): y=0 -> xpG [m][1024] gate-row-major (biases folded),
// y=1 -> backward single-step cell -> hb, y=2 -> fc_w fp32->bf16
// (grid-stride, overlaps the other planes; was the serialized k3).
// --------------------------------------------------------------------------
__global__ __launch_bounds__(256) void k1_embproj(
    const int* __restrict__ x, const float* __restrict__ embed,
    const float4* __restrict__ wPackF, const float4* __restrict__ wPackB,
    const float4* __restrict__ biasF, const float4* __restrict__ biasB,
    float* __restrict__ xpG, unsigned short* __restrict__ outB,
    const float4* __restrict__ fcw, uint2* __restrict__ fcwB)
{
  __shared__ __align__(16) float e[16][256];
  __shared__ int xi[16];
  const int j = threadIdx.x;
  const int dir = blockIdx.y;

  if (dir == 2) {
    // fused fc_w fp32 -> bf16: 4,096,000 float4 over 128 blocks x 256 thr
    for (size_t i = (size_t)blockIdx.x * 256 + j; i < 4096000u; i += 32768u) {
      const float4 v = fcw[i];
      uint2 r;
      r.x = (unsigned)f2bf(v.x) | ((unsigned)f2bf(v.y) << 16);
      r.y = (unsigned)f2bf(v.z) | ((unsigned)f2bf(v.w) << 16);
      fcwB[i] = r;
    }
    return;
  }

  const int m0 = blockIdx.x * 16;
  if (j < 16) xi[j] = x[m0 + j];
  __syncthreads();
#pragma unroll
  for (int m = 0; m < 16; ++m) e[m][j] = embed[(size_t)xi[m] * Dd + j];
  __syncthreads();

  const float4* wP = dir ? wPackB : wPackF;
  float4 acc[16];
#pragma unroll
  for (int m = 0; m < 16; ++m) acc[m] = make_float4(0.f, 0.f, 0.f, 0.f);

  for (int k = 0; k < 256; k += 4) {
    const float4 w0 = wP[(k + 0) * 256 + j];
    const float4 w1 = wP[(k + 1) * 256 + j];
    const float4 w2 = wP[(k + 2) * 256 + j];
    const float4 w3 = wP[(k + 3) * 256 + j];
#pragma unroll
    for (int m = 0; m < 16; ++m) {
      const float4 e4 = *(const float4*)&e[m][k];
      fma4(acc[m], w0, e4.x); fma4(acc[m], w1, e4.y);
      fma4(acc[m], w2, e4.z); fma4(acc[m], w3, e4.w);
    }
  }

  if (dir == 0) {
    const float4 bv = biasF[j];
#pragma unroll
    for (int m = 0; m < 16; ++m) {
      float4 v = acc[m];
      float* xq = xpG + (size_t)(m0 + m) * 1024 + j;
      xq[0]   = v.x + bv.x;
      xq[256] = v.y + bv.y;
      xq[512] = v.z + bv.z;
      xq[768] = v.w + bv.w;
    }
  } else {
    const float4 bv = biasB[j];
#pragma unroll
    for (int m = 0; m < 16; ++m) {
      float4 v = acc[m];
      v.x += bv.x; v.y += bv.y; v.z += bv.z; v.w += bv.w;
      const float ig = sigm(v.x);
      const float gg = tanh_(v.z);
      const float og = sigm(v.w);
      const float hb = og * tanh_(ig * gg);
      outB[(size_t)(m0 + m) * Ktot + Hh + j] = f2bf(hb);
    }
  }
}

// --------------------------------------------------------------------------
// KW: W_hh fp32 [1024][256] -> packed f16, q-major layout [32][1024] uint4
// (q = k/8).  wq[q*1024 + row] = 8 f16 of row `row`, k in [8q, 8q+8).
// --------------------------------------------------------------------------
__global__ __launch_bounds__(256) void kw_cvt(const float4* __restrict__ s,
                                              uint4* __restrict__ d)
{
  const int g = blockIdx.x * 256 + threadIdx.x;   // 0..32767
  const int row = g & 1023;
  const int qq  = g >> 10;                        // 0..31
  const float4 a = s[row * 64 + qq * 2];
  const float4 b = s[row * 64 + qq * 2 + 1];
  uint4 r;
  r.x = pkh(a.x, a.y);
  r.y = pkh(a.z, a.w);
  r.z = pkh(b.x, b.y);
  r.w = pkh(b.z, b.w);
  d[g] = r;
}

// --------------------------------------------------------------------------
// K2h: forward LSTM scan, ONE block per batch (16 blocks x 512 threads,
// 8 waves = 2/SIMD).  Thread (u=tid&255, p=tid>>8) owns gate rows
// p*512+u (i or g) and p*512+256+u (f or o).
// Weights: 2x23 chunks in VGPRs (184 regs), 2x9 chunks in LDS (147KB).
// h broadcast: 1 cooperative ds_read_b64/wave then v_readlane -> SGPR
// operand of v_pk_fma_f16.  2 lgkm-only barriers/step.
// amdgpu_waves_per_eu(1) (min-only): remove the max-occupancy constraint
// so the allocator may grant ~230 ARCH VGPRs (2x230 <= 512 unified file
// still runs 2 waves/EU).  (2,2) and default both pinned arch at 128 and
// put ~150 weight dwords in AGPRs -> v_accvgpr_read tax every step.
// --------------------------------------------------------------------------
__global__ __launch_bounds__(512)
__attribute__((amdgpu_waves_per_eu(1)))
void k2h(
    const uint4* __restrict__ wq,     // [32][1024] uint4 packed f16 W_hh
    const float* __restrict__ xpG,    // [2048][1024]
    unsigned short* __restrict__ outB)
{
  __shared__ __align__(16) uint4 wl[2 * NW_L * 512];    // 147456 B
  __shared__ __align__(8)  float2 gox[256];             // g,o preacts (p=1 -> p=0)
  __shared__ __align__(8)  unsigned short hL[256];      // h_t as f16 bits

  const int tid = threadIdx.x;
  const int u = tid & 255;
  const int p = tid >> 8;
  const int b = blockIdx.x;
  const int rowA = p * 512 + u;         // gate i (p=0) / g (p=1)
  const int rowB = rowA + 256;          // gate f (p=0) / o (p=1)

  // one-time: weights into VGPRs (46 uint4 = 184 regs) -- coalesced
  uint4 wvA[NW_V], wvB[NW_V];
#pragma unroll
  for (int q = 0; q < NW_V; ++q) wvA[q] = wq[q * 1024 + rowA];
#pragma unroll
  for (int q = 0; q < NW_V; ++q) wvB[q] = wq[q * 1024 + rowB];
  // one-time: weight tail into LDS (18 uint4/thread)
#pragma unroll
  for (int j = 0; j < NW_L; ++j)
    wl[j * 512 + tid] = wq[(NW_V + j) * 1024 + rowA];
#pragma unroll
  for (int j = 0; j < NW_L; ++j)
    wl[(NW_L + j) * 512 + tid] = wq[(NW_V + j) * 1024 + rowB];

  const float* xpB = xpG + (size_t)b * Sq * 1024;
  float xa = xpB[rowA];                 // xp prefetch for t=0
  float xb = xpB[rowB];
  float cst = 0.f;                      // cell state (p=0 threads)
  unsigned short* oB = outB + (size_t)b * Sq * Ktot;

  unsigned hx = 0, hy = 0;              // lane-coop h: lane l holds dwords 2l,2l+1
  bar();                                // wl staged

  const f16x2 z2 = __builtin_bit_cast(f16x2, 0u);

#pragma unroll 1
  for (int t = 0; t < Sq; ++t) {
    // dot: 512 MACs/thread = 256 v_pk_fma_f16, h via readlane->SGPR.
    // Chunk q covers k in [8q,8q+8) = h dwords 4q..4q+3:
    //   dword 4q+d: lane 2q+(d>>1), reg (d&1 ? hy : hx).
    f16x2 aA0 = z2, aA1 = z2, aA2 = z2, aA3 = z2;
    f16x2 aB0 = z2, aB1 = z2, aB2 = z2, aB3 = z2;
#pragma unroll
    for (int q = 0; q < NW_V; ++q) {
      const unsigned s0 = __builtin_amdgcn_readlane(hx, 2 * q);
      const unsigned s1 = __builtin_amdgcn_readlane(hy, 2 * q);
      const unsigned s2 = __builtin_amdgcn_readlane(hx, 2 * q + 1);
      const unsigned s3 = __builtin_amdgcn_readlane(hy, 2 * q + 1);
      aA0 = fma2(wvA[q].x, s0, aA0); aB0 = fma2(wvB[q].x, s0, aB0);
      aA1 = fma2(wvA[q].y, s1, aA1); aB1 = fma2(wvB[q].y, s1, aB1);
      aA2 = fma2(wvA[q].z, s2, aA2); aB2 = fma2(wvB[q].z, s2, aB2);
      aA3 = fma2(wvA[q].w, s3, aA3); aB3 = fma2(wvB[q].w, s3, aB3);
    }
#pragma unroll
    for (int j = 0; j < NW_L; ++j) {
      const int q = NW_V + j;
      const uint4 wA = wl[j * 512 + tid];              // conflict-free 16B/lane
      const uint4 wB = wl[(NW_L + j) * 512 + tid];
      const unsigned s0 = __builtin_amdgcn_readlane(hx, 2 * q);
      const unsigned s1 = __builtin_amdgcn_readlane(hy, 2 * q);
      const unsigned s2 = __builtin_amdgcn_readlane(hx, 2 * q + 1);
      const unsigned s3 = __builtin_amdgcn_readlane(hy, 2 * q + 1);
      aA0 = fma2(wA.x, s0, aA0); aB0 = fma2(wB.x, s0, aB0);
      aA1 = fma2(wA.y, s1, aA1); aB1 = fma2(wB.y, s1, aB1);
      aA2 = fma2(wA.z, s2, aA2); aB2 = fma2(wB.z, s2, aB2);
      aA3 = fma2(wA.w, s3, aA3); aB3 = fma2(wB.w, s3, aB3);
    }
    const float preA = xa
        + (((float)aA0.x + (float)aA0.y) + ((float)aA1.x + (float)aA1.y))
        + (((float)aA2.x + (float)aA2.y) + ((float)aA3.x + (float)aA3.y));
    const float preB = xb
        + (((float)aB0.x + (float)aB0.y) + ((float)aB1.x + (float)aB1.y))
        + (((float)aB2.x + (float)aB2.y) + ((float)aB3.x + (float)aB3.y));

    // prefetch next step's xp (vmcnt -- survives the lgkm-only barriers)
    {
      const float* xn = xpB + (size_t)((t + 1) & (Sq - 1)) * 1024;
      xa = xn[rowA]; xb = xn[rowB];
    }

    if (p) gox[u] = make_float2(preA, preB);   // publish g,o preacts
    bar();   // #1

    if (!p) {
      const float2 go = gox[u];
      const float ig = sigm(preA);        // i
      const float fg = sigm(preB);        // f
      const float gg = tanh_(go.x);       // g
      const float og = sigm(go.y);        // o
      cst = fg * cst + ig * gg;
      const float hn = og * tanh_(cst);
      hL[u] = __builtin_bit_cast(unsigned short, (_Float16)hn);
      oB[t * Ktot + u] = f2bf(hn);
    }
    bar();   // #2: h_t published

    // cooperative h pickup for step t+1: 8B/lane, 2-way bank alias (free)
    {
      const uint2 hv2 = *(const uint2*)((const char*)hL + ((tid & 63) * 8));
      hx = hv2.x; hy = hv2.y;
    }
  }
}

// --------------------------------------------------------------------------
// K4: logits = [2048,512](bf16) x fc_w^T (fc_w [32000,512] bf16, B^T layout)
// + fc_b.  128x128 tile, BK=64, 4 waves, global_load_lds width-16 staging.
// 1D grid 4000 with bijective XCD swizzle: swz=(g%8)*500+g/8 -> each XCD
// gets a contiguous swz range -> all 16 bm-tiles of a bn on one XCD-L2.
// --------------------------------------------------------------------------
__device__ __forceinline__ void load_lds_16(const void* g, void* l) {
  __builtin_amdgcn_global_load_lds(
      (const __attribute__((address_space(1))) unsigned int*)g,
      (__attribute__((address_space(3))) unsigned int*)l, 16, 0, 0);
}

__global__ __launch_bounds__(256) void k4_gemm(
    const unsigned short* __restrict__ A,   // [2048][512] bf16
    const unsigned short* __restrict__ Bm,  // [32000][512] bf16
    const float* __restrict__ fcb,          // [32000]
    float* __restrict__ out)                // [2048][32000]
{
  __shared__ __align__(16) char smem[32768];
  const int tid  = threadIdx.x;
  const int wave = tid >> 6;
  const int lane = tid & 63;
  const int g0   = blockIdx.x;            // 0..3999
  const int swz  = (g0 & 7) * 500 + (g0 >> 3);   // bijective (4000 = 8*500)
  const int bm = swz & 15;                // 0..15  (M tiles)
  const int bn = swz >> 4;                // 0..249 (N tiles)
  const int wm = (wave >> 1) * 64;
  const int wn = (wave & 1) * 64;
  const int quad = lane >> 4;
  const int r16  = lane & 15;

  f32x4 acc[4][4] = {};

  const unsigned short* Ag = A  + ((size_t)(bm * 128) + (tid >> 3)) * Ktot + (tid & 7) * 8;
  const unsigned short* Bg = Bm + ((size_t)(bn * 128) + (tid >> 3)) * Ktot + (tid & 7) * 8;
  char* AsW = smem + wave * 1024;
  char* BsW = smem + 16384 + wave * 1024;

  for (int kt = 0; kt < 8; ++kt) {
    const int k0 = kt * 64;
#pragma unroll
    for (int r = 0; r < 4; ++r) {
      load_lds_16(Ag + (size_t)r * 32 * Ktot + k0, AsW + r * 4096);
      load_lds_16(Bg + (size_t)r * 32 * Ktot + k0, BsW + r * 4096);
    }
    __syncthreads();
#pragma unroll
    for (int kk = 0; kk < 2; ++kk) {
      bf16x8 af[4], bfr[4];
#pragma unroll
      for (int i = 0; i < 4; ++i) {
        const int rowA = wm + i * 16 + r16;
        af[i] = *(const bf16x8*)(smem + rowA * 128 + kk * 64 + quad * 16);
        const int rowB = wn + i * 16 + r16;
        bfr[i] = *(const bf16x8*)(smem + 16384 + rowB * 128 + kk * 64 + quad * 16);
      }
#pragma unroll
      for (int i = 0; i < 4; ++i)
#pragma unroll
        for (int j = 0; j < 4; ++j)
          acc[i][j] = __builtin_amdgcn_mfma_f32_16x16x32_bf16(af[i], bfr[j], acc[i][j], 0, 0, 0);
    }
    __syncthreads();
  }

#pragma unroll
  for (int j = 0; j < 4; ++j) {
    const int col = bn * 128 + wn + j * 16 + r16;
    const float bias = fcb[col];
#pragma unroll
    for (int i = 0; i < 4; ++i) {
      const int row0 = bm * 128 + wm + i * 16 + quad * 4;
#pragma unroll
      for (int r = 0; r < 4; ++r) {
        out[(size_t)(row0 + r) * Vv + col] = acc[i][j][r] + bias;
      }
    }
  }
}

// --------------------------------------------------------------------------
extern "C" void kernel_launch(void* const* d_in, const int* in_sizes, int n_in,
                              void* d_out, int out_size, void* d_ws, size_t ws_size,
                              hipStream_t stream) {
  const int*   x      = (const int*)d_in[0];
  const float* embed  = (const float*)d_in[1];
  const float* w_ih_f = (const float*)d_in[2];
  const float* w_hh_f = (const float*)d_in[3];
  const float* b_ih_f = (const float*)d_in[4];
  const float* b_hh_f = (const float*)d_in[5];
  const float* w_ih_b = (const float*)d_in[6];
  // d_in[7] = w_hh_b: unused (backward direction is a zero-state single step)
  const float* b_ih_b = (const float*)d_in[8];
  const float* b_hh_b = (const float*)d_in[9];
  const float* fc_w   = (const float*)d_in[10];
  const float* fc_b   = (const float*)d_in[11];
  float* out = (float*)d_out;

  // Workspace layout (peak 45.4 MB; wq overlays wPackF which is dead after
  // k1 -- kw_cvt MUST launch after k1):
  char* ws = (char*)d_ws;
  float4* wPackF = (float4*)(ws + 0x000000);            // 1 MB   (k0 w, k1 r)
  float4* wPackB = (float4*)(ws + 0x100000);            // 1 MB   (k0 w, k1 r)
  uint4*  wq     = (uint4*)(ws + 0x000000);             // 512 KB (kw w, k2 r)
  float*  xpG    = (float*)(ws + 0x200000);             // 8 MB   (k1 w, k2 r)
  float4* biasF  = (float4*)(ws + 0xA00000);            // 4 KB
  float4* biasB  = (float4*)(ws + 0xA01000);            // 4 KB
  unsigned short* outB = (unsigned short*)(ws + 0xA05000);   // 2 MB [2048][512]
  unsigned short* fcwB = (unsigned short*)(ws + 0xC05000);   // 31.25 MiB

  k0_pack<<<dim3(256, 2), 256, 0, stream>>>(w_ih_f, w_ih_b,
                                            b_ih_f, b_hh_f, b_ih_b, b_hh_b,
                                            wPackF, wPackB, biasF, biasB);
  k1_embproj<<<dim3(128, 3), 256, 0, stream>>>(x, embed, wPackF, wPackB,
                                               biasF, biasB, xpG, outB,
                                               (const float4*)fc_w, (uint2*)fcwB);
  kw_cvt<<<128, 256, 0, stream>>>((const float4*)w_hh_f, wq);
  k2h<<<16, 512, 0, stream>>>(wq, xpG, outB);
  k4_gemm<<<4000, 256, 0, stream>>>(outB, fcwB, fc_b, out);
}